// Round 6
// baseline (554.560 us; speedup 1.0000x reference)
//
#include <hip/hip_runtime.h>
#include <hip/hip_fp16.h>

#define B_  32
#define N_  256
#define HS_ 768
#define NH_ 32
#define D_  24
#define M_  (B_*N_)   // 8192
#define QKVN 2304

typedef unsigned short us8 __attribute__((ext_vector_type(8)));
typedef _Float16 f16x8 __attribute__((ext_vector_type(8)));
typedef float f32x4 __attribute__((ext_vector_type(4)));

__device__ __forceinline__ unsigned short f2h(float x){
  return __half_as_ushort(__float2half(x));
}
__device__ __forceinline__ float h2f(unsigned short u){
  return __half2float(__ushort_as_half(u));
}
__device__ __forceinline__ void gload16(const void* g, void* l){
  __builtin_amdgcn_global_load_lds(
      (const __attribute__((address_space(1))) void*)g,
      (__attribute__((address_space(3))) void*)l, 16, 0, 0);
}

// ---------------- fp32 -> fp16-bits conversion ----------------
__global__ __launch_bounds__(256) void cvt_kernel(const float* __restrict__ in,
                                                  unsigned short* __restrict__ out, int n4){
  int i = blockIdx.x*256 + threadIdx.x;
  if (i >= n4) return;
  float4 v = ((const float4*)in)[i];
  ushort4 o;
  o.x = f2h(v.x); o.y = f2h(v.y); o.z = f2h(v.z); o.w = f2h(v.w);
  ((ushort4*)out)[i] = o;
}

// ---------------- GEMM 128x128, BK=64, global_load_lds, XOR-swizzled LDS ----------------
__global__ __launch_bounds__(256) void gemm128_kernel(
    const unsigned short* __restrict__ A, const unsigned short* __restrict__ W,
    const float* __restrict__ b0, const float* __restrict__ b1, const float* __restrict__ b2,
    unsigned short* __restrict__ C, int M, int N, int K, int dogelu)
{
  __shared__ unsigned short As[128*64];
  __shared__ unsigned short Bs[128*64];
  int gswz = blockIdx.x;
  int chunkg = gridDim.x >> 3;
  int bid = (gswz & 7)*chunkg + (gswz >> 3);
  int tid = threadIdx.x;
  int nT = N >> 7;
  int tm = bid / nT;
  int tn = bid - tm*nT;
  int which = (tn << 7) / 768;
  const float* bp = (which == 0) ? b0 : (which == 1) ? b1 : b2;
  bp -= which * 768;
  int wave = tid >> 6, lane = tid & 63;
  int wm = (wave >> 1) << 6;
  int wn = (wave & 1) << 6;
  int fr = lane & 15;
  int g  = lane >> 4;

  size_t aoff[4], woff[4];
  int ldsb[4];
#pragma unroll
  for (int s4 = 0; s4 < 4; s4++){
    int ob = s4*4096 + tid*16;
    int r  = ob >> 7;
    int p  = (ob >> 4) & 7;
    int l  = p ^ (r & 7);
    aoff[s4] = ((size_t)(tm*128 + r)*K)*2 + l*16;
    woff[s4] = ((size_t)(tn*128 + r)*K)*2 + l*16;
    ldsb[s4] = s4*4096 + wave*1024;
  }
  const char* Ab = (const char*)A;
  const char* Wb = (const char*)W;
  char* AsB = (char*)As;
  char* BsB = (char*)Bs;

  f32x4 acc[4][4];
#pragma unroll
  for (int m = 0; m < 4; m++)
#pragma unroll
    for (int n = 0; n < 4; n++) acc[m][n] = (f32x4){0.f,0.f,0.f,0.f};

  for (int k0 = 0; k0 < K; k0 += 64){
    size_t kb = (size_t)k0*2;
#pragma unroll
    for (int s4 = 0; s4 < 4; s4++) gload16(Ab + aoff[s4] + kb, AsB + ldsb[s4]);
#pragma unroll
    for (int s4 = 0; s4 < 4; s4++) gload16(Wb + woff[s4] + kb, BsB + ldsb[s4]);
    __syncthreads();

    f16x8 af[4], bf[4];
#pragma unroll
    for (int m = 0; m < 4; m++){
      int row = wm + m*16 + fr;
      af[m] = __builtin_bit_cast(f16x8, *(const us8*)(AsB + row*128 + ((g ^ (row & 7))*16)));
    }
#pragma unroll
    for (int n = 0; n < 4; n++){
      int row = wn + n*16 + fr;
      bf[n] = __builtin_bit_cast(f16x8, *(const us8*)(BsB + row*128 + ((g ^ (row & 7))*16)));
    }
#pragma unroll
    for (int m = 0; m < 4; m++)
#pragma unroll
      for (int n = 0; n < 4; n++)
        acc[m][n] = __builtin_amdgcn_mfma_f32_16x16x32_f16(af[m], bf[n], acc[m][n], 0, 0, 0);

#pragma unroll
    for (int m = 0; m < 4; m++){
      int row = wm + m*16 + fr;
      af[m] = __builtin_bit_cast(f16x8, *(const us8*)(AsB + row*128 + (((g+4) ^ (row & 7))*16)));
    }
#pragma unroll
    for (int n = 0; n < 4; n++){
      int row = wn + n*16 + fr;
      bf[n] = __builtin_bit_cast(f16x8, *(const us8*)(BsB + row*128 + (((g+4) ^ (row & 7))*16)));
    }
#pragma unroll
    for (int m = 0; m < 4; m++)
#pragma unroll
      for (int n = 0; n < 4; n++)
        acc[m][n] = __builtin_amdgcn_mfma_f32_16x16x32_f16(af[m], bf[n], acc[m][n], 0, 0, 0);
    __syncthreads();
  }

#pragma unroll
  for (int n = 0; n < 4; n++){
    int col = tn*128 + wn + n*16 + fr;
    float bv = bp[col];
#pragma unroll
    for (int m = 0; m < 4; m++){
      int row = tm*128 + wm + m*16 + g*4;
#pragma unroll
      for (int q = 0; q < 4; q++){
        float v = acc[m][n][q] + bv;
        if (dogelu) v = 0.5f*v*(1.0f + erff(v*0.70710678118654752f));
        C[(size_t)(row + q)*N + col] = f2h(v);
      }
    }
  }
}

// ---------------- prep: u_c[b,h,j] = sum_d v*Wf_c ; negv[b,j] ----------------
__global__ __launch_bounds__(256) void prep_kernel(
    const unsigned short* __restrict__ qkv, const float* __restrict__ mask,
    const float* __restrict__ Wf1, const float* __restrict__ Wf2, const float* __restrict__ Wf3,
    float* __restrict__ uarr,   // [B*NH][3][N]
    float* __restrict__ negv)   // [B][N]
{
  int bh = blockIdx.x;
  int h = bh & 31, b = bh >> 5;
  int j = threadIdx.x;
  const unsigned short* vr = qkv + (size_t)(b*N_ + j)*QKVN + 1536 + h*D_;
  us8 v0 = *(const us8*)(vr);
  us8 v1 = *(const us8*)(vr + 8);
  us8 v2 = *(const us8*)(vr + 16);
  const float* w1 = Wf1 + h*D_;
  const float* w2 = Wf2 + h*D_;
  const float* w3 = Wf3 + h*D_;
  float u0 = 0.f, u1 = 0.f, u2 = 0.f;
#pragma unroll
  for (int e = 0; e < 8; e++){
    float va = h2f(v0[e]), vb2 = h2f(v1[e]), vc = h2f(v2[e]);
    u0 += va*w1[e] + vb2*w1[8+e] + vc*w1[16+e];
    u1 += va*w2[e] + vb2*w2[8+e] + vc*w2[16+e];
    u2 += va*w3[e] + vb2*w3[8+e] + vc*w3[16+e];
  }
  float* ub = uarr + (size_t)bh*3*N_;
  ub[j] = u0; ub[N_ + j] = u1; ub[2*N_ + j] = u2;
  if (h == 0) negv[b*N_ + j] = (1.0f - mask[b*N_ + j]) * -100000.0f;
}

// ---------------- attention + fused epilogue ----------------
// grid: B*NH = 1024 (XCD-chunked: same-b blocks share an XCD for dp L2 reuse).
// block: 256 thr = 4 waves. Wave w owns 16 rows x 256 cols; loops 4 row-tiles.
// K/Q/u/neg staged once; softmax reductions are in-wave shfl only (no mid barriers).
#define SCALE 0.20412414523193154f   // 24^-0.5
#define INVSCALE 4.898979485566356f  // sqrt(24)
__global__ __launch_bounds__(256, 2) void attn_kernel(
    const unsigned short* __restrict__ qkv,
    const float* __restrict__ bias,
    const float* __restrict__ uarr, const float* __restrict__ negv,
    const float* __restrict__ dp,
    float* __restrict__ fpart)
{
  int gswz = blockIdx.x;
  int lin = (gswz & 7)*128 + (gswz >> 3);   // 1024 = 8*128; 4 b's per XCD
  int h = lin & 31, b = lin >> 5;
  int t = threadIdx.x;

  __shared__ us8 Kp[256][5];      // 20 KB (chunk3 = zeros, stride pad)
  __shared__ us8 Qp[256][5];      // 20 KB
  __shared__ float u0s[256], u1s[256], u2s[256];
  __shared__ float negs[256];

  // --- stage everything once ---
  {
    us8 z = {0,0,0,0,0,0,0,0};
    const unsigned short* kr = qkv + (size_t)(b*N_ + t)*QKVN + 768 + h*D_;
    Kp[t][0] = *(const us8*)(kr);
    Kp[t][1] = *(const us8*)(kr + 8);
    Kp[t][2] = *(const us8*)(kr + 16);
    Kp[t][3] = z;
    const unsigned short* qr = kr - 768;
    Qp[t][0] = *(const us8*)(qr);
    Qp[t][1] = *(const us8*)(qr + 8);
    Qp[t][2] = *(const us8*)(qr + 16);
    Qp[t][3] = z;
    const float* ub = uarr + (size_t)lin*3*N_;
    u0s[t] = ub[t];
    u1s[t] = ub[N_ + t];
    u2s[t] = ub[2*N_ + t];
    negs[t] = negv[b*N_ + t];
  }
  __syncthreads();

  int wave = t >> 6, lane = t & 63;
  int fr = lane & 15, g = lane >> 4;

#pragma unroll 1
  for (int tile = 0; tile < 4; tile++){
    int i = tile*64 + wave*16 + fr;     // query row 0..255
    const float4* bias4 = (const float4*)(bias + ((size_t)lin*N_ + i)*N_);
    f16x8 qf = __builtin_bit_cast(f16x8, Qp[i][g]);
    f32x4 s[16];

    // scores, two halves of 8 jt; bias+neg folded into MFMA C-in
#pragma unroll
    for (int half = 0; half < 2; half++){
      float4 bvv[8];
#pragma unroll
      for (int q = 0; q < 8; q++) bvv[q] = bias4[(half*8 + q)*4 + g];
#pragma unroll
      for (int q = 0; q < 8; q++){
        int jt = half*8 + q;
        int jb = jt*16 + g*4;
        float4 nv = *(const float4*)&negs[jb];
        f32x4 cin;
        cin[0] = (bvv[q].x + nv.x)*INVSCALE;
        cin[1] = (bvv[q].y + nv.y)*INVSCALE;
        cin[2] = (bvv[q].z + nv.z)*INVSCALE;
        cin[3] = (bvv[q].w + nv.w)*INVSCALE;
        f16x8 kf = __builtin_bit_cast(f16x8, Kp[jt*16 + fr][g]);
        s[jt] = __builtin_amdgcn_mfma_f32_16x16x32_f16(kf, qf, cin, 0, 0, 0);
      }
    }

    // row max (in-wave only: 4 col-groups)
    float m = -3.0e38f;
#pragma unroll
    for (int jt = 0; jt < 16; jt++)
      m = fmaxf(m, fmaxf(fmaxf(s[jt][0], s[jt][1]), fmaxf(s[jt][2], s[jt][3])));
    m = fmaxf(m, __shfl_xor(m, 16));
    m = fmaxf(m, __shfl_xor(m, 32));

    // exp + sum + fused dp/u accumulation, 4 groups of 4 jt
    const float* dpb = dp + (size_t)(b*N_ + i) * (N_*3);
    float sum = 0.f, a0 = 0.f, a1 = 0.f, a2 = 0.f;
#pragma unroll
    for (int gr = 0; gr < 4; gr++){
      float4 dbuf[12];
#pragma unroll
      for (int q = 0; q < 4; q++){
        int j0 = (gr*4 + q)*16 + g*4;
        const float4* dq = (const float4*)(dpb + j0*3);
        dbuf[q*3+0] = dq[0]; dbuf[q*3+1] = dq[1]; dbuf[q*3+2] = dq[2];
      }
#pragma unroll
      for (int q = 0; q < 4; q++){
        int jt = gr*4 + q;
        int j0 = jt*16 + g*4;
        float p0 = __expf((s[jt][0] - m)*SCALE);
        float p1 = __expf((s[jt][1] - m)*SCALE);
        float p2 = __expf((s[jt][2] - m)*SCALE);
        float p3 = __expf((s[jt][3] - m)*SCALE);
        sum += p0 + p1 + p2 + p3;
        float4 d0 = dbuf[q*3], d1 = dbuf[q*3+1], d2 = dbuf[q*3+2];
        float4 u0v = *(const float4*)&u0s[j0];
        float4 u1v = *(const float4*)&u1s[j0];
        float4 u2v = *(const float4*)&u2s[j0];
        a0 += p0*u0v.x*d0.x + p1*u0v.y*d0.w + p2*u0v.z*d1.z + p3*u0v.w*d2.y;
        a1 += p0*u1v.x*d0.y + p1*u1v.y*d1.x + p2*u1v.z*d1.w + p3*u1v.w*d2.z;
        a2 += p0*u2v.x*d0.z + p1*u2v.y*d1.y + p2*u2v.z*d2.x + p3*u2v.w*d2.w;
      }
    }
    sum += __shfl_xor(sum, 16); sum += __shfl_xor(sum, 32);
    a0  += __shfl_xor(a0, 16);  a0  += __shfl_xor(a0, 32);
    a1  += __shfl_xor(a1, 16);  a1  += __shfl_xor(a1, 32);
    a2  += __shfl_xor(a2, 16);  a2  += __shfl_xor(a2, 32);
    if (lane < 16){
      float rs = 1.0f / sum;
      float* fp = fpart + ((size_t)lin*N_ + i)*3;
      fp[0] = a0*rs; fp[1] = a1*rs; fp[2] = a2*rs;
    }
  }
}

// ---------------- final cross-head reduction ----------------
__global__ __launch_bounds__(256) void final_kernel(const float* __restrict__ fpart,
    const float* __restrict__ bf1, const float* __restrict__ bf2, const float* __restrict__ bf3,
    float* __restrict__ out)
{
  int idx = blockIdx.x*256 + threadIdx.x;
  if (idx >= B_*N_*3) return;
  int c = idx % 3;
  int bi = idx / 3;
  int b = bi >> 8, ii = bi & 255;
  float sacc = (c == 0) ? bf1[0] : (c == 1) ? bf2[0] : bf3[0];
#pragma unroll 8
  for (int hh = 0; hh < NH_; hh++){
    sacc += fpart[(((size_t)(b*NH_ + hh))*N_ + ii)*3 + c];
  }
  out[idx] = sacc;
}

extern "C" void kernel_launch(void* const* d_in, const int* in_sizes, int n_in,
                              void* d_out, int out_size, void* d_ws, size_t ws_size,
                              hipStream_t stream)
{
  const float* X    = (const float*)d_in[0];
  const float* bias = (const float*)d_in[1];
  const float* dp   = (const float*)d_in[2];
  const float* mask = (const float*)d_in[3];
  const float* Wi   = (const float*)d_in[4];
  const float* bi   = (const float*)d_in[5];
  const float* Wq   = (const float*)d_in[6];
  const float* bq   = (const float*)d_in[7];
  const float* Wk   = (const float*)d_in[8];
  const float* bk   = (const float*)d_in[9];
  const float* Wv   = (const float*)d_in[10];
  const float* bv   = (const float*)d_in[11];
  const float* Wf1  = (const float*)d_in[12];
  const float* bf1  = (const float*)d_in[13];
  const float* Wf2  = (const float*)d_in[14];
  const float* bf2  = (const float*)d_in[15];
  const float* Wf3  = (const float*)d_in[16];
  const float* bf3  = (const float*)d_in[17];
  float* out = (float*)d_out;

  unsigned short* xb   = (unsigned short*)d_ws;
  unsigned short* wib  = xb   + (size_t)M_*HS_;
  unsigned short* wqb  = wib  + (size_t)HS_*HS_;
  unsigned short* wkb  = wqb  + (size_t)HS_*HS_;
  unsigned short* wvb  = wkb  + (size_t)HS_*HS_;
  unsigned short* hb   = wvb  + (size_t)HS_*HS_;
  unsigned short* qkvb = hb   + (size_t)M_*HS_;
  float* fpart = (float*)(qkvb + (size_t)M_*QKVN);
  float* uarr  = fpart + (size_t)B_*NH_*N_*3;
  float* negv  = uarr + (size_t)B_*NH_*3*N_;

  {
    int n4 = M_*HS_/4;
    cvt_kernel<<<n4/256, 256, 0, stream>>>(X, xb, n4);
    int w4 = HS_*HS_/4;
    cvt_kernel<<<w4/256, 256, 0, stream>>>(Wi, wib, w4);
    cvt_kernel<<<w4/256, 256, 0, stream>>>(Wq, wqb, w4);
    cvt_kernel<<<w4/256, 256, 0, stream>>>(Wk, wkb, w4);
    cvt_kernel<<<w4/256, 256, 0, stream>>>(Wv, wvb, w4);
  }

  // h = gelu(X Wi^T + bi):  grid 64*6 = 384 (%8==0)
  gemm128_kernel<<<(M_/128)*(HS_/128), 256, 0, stream>>>(xb, wib, bi, bi, bi, hb, M_, HS_, HS_, 1);
  // qkv = h [Wq;Wk;Wv]^T + bias:  grid 64*18 = 1152 (%8==0)
  gemm128_kernel<<<(M_/128)*(QKVN/128), 256, 0, stream>>>(hb, wqb, bq, bk, bv, qkvb, M_, QKVN, HS_, 0);

  prep_kernel<<<B_*NH_, 256, 0, stream>>>(qkvb, mask, Wf1, Wf2, Wf3, uarr, negv);

  attn_kernel<<<B_*NH_, 256, 0, stream>>>(qkvb, bias, uarr, negv, dp, fpart);

  final_kernel<<<(B_*N_*3 + 255)/256, 256, 0, stream>>>(fpart, bf1, bf2, bf3, out);
}

// Round 7
// 242.871 us; speedup vs baseline: 2.2834x; 2.2834x over previous
//
#include <hip/hip_runtime.h>
#include <hip/hip_fp16.h>

#define B_  32
#define N_  256
#define HS_ 768
#define NH_ 32
#define D_  24
#define M_  (B_*N_)   // 8192
#define QKVN 2304

typedef unsigned short us8 __attribute__((ext_vector_type(8)));
typedef unsigned short us4v __attribute__((ext_vector_type(4)));
typedef _Float16 f16x8 __attribute__((ext_vector_type(8)));
typedef float f32x4 __attribute__((ext_vector_type(4)));

__device__ __forceinline__ unsigned short f2h(float x){
  return __half_as_ushort(__float2half(x));
}
__device__ __forceinline__ float h2f(unsigned short u){
  return __half2float(__ushort_as_half(u));
}
__device__ __forceinline__ void gload16(const void* g, void* l){
  __builtin_amdgcn_global_load_lds(
      (const __attribute__((address_space(1))) void*)g,
      (__attribute__((address_space(3))) void*)l, 16, 0, 0);
}

// ---------------- fp32 -> fp16-bits conversion ----------------
__global__ __launch_bounds__(256) void cvt_kernel(const float* __restrict__ in,
                                                  unsigned short* __restrict__ out, int n4){
  int i = blockIdx.x*256 + threadIdx.x;
  if (i >= n4) return;
  float4 v = ((const float4*)in)[i];
  ushort4 o;
  o.x = f2h(v.x); o.y = f2h(v.y); o.z = f2h(v.z); o.w = f2h(v.w);
  ((ushort4*)out)[i] = o;
}

// ---------------- dp fp32 [b,i,j,c] -> fp16 planes dpH[b][c][i][j] ----------------
__global__ __launch_bounds__(256) void cvt_dp_kernel(const float* __restrict__ dp,
                                                     unsigned short* __restrict__ dpH){
  int idx = blockIdx.x*256 + threadIdx.x;       // B*N*64
  int row = idx >> 6, jg = idx & 63;            // row = b*256+i
  int b = row >> 8, i = row & 255;
  const float4* src = (const float4*)dp + (size_t)row*192 + jg*3;
  float4 a = src[0], bb = src[1], c = src[2];
  int j0 = jg*4;
  us4v o0 = {f2h(a.x), f2h(a.w), f2h(bb.z), f2h(c.y)};
  us4v o1 = {f2h(a.y), f2h(bb.x), f2h(bb.w), f2h(c.z)};
  us4v o2 = {f2h(a.z), f2h(bb.y), f2h(c.x), f2h(c.w)};
  size_t p = ((size_t)(b*3)*N_ + i)*N_ + j0;
  *(us4v*)(dpH + p) = o0;
  *(us4v*)(dpH + p + (size_t)N_*N_) = o1;
  *(us4v*)(dpH + p + 2*(size_t)N_*N_) = o2;
}

// ---------------- GEMM 128x128, BK=64, global_load_lds, XOR-swizzled LDS ----------------
__global__ __launch_bounds__(256) void gemm128_kernel(
    const unsigned short* __restrict__ A, const unsigned short* __restrict__ W,
    const float* __restrict__ b0, const float* __restrict__ b1, const float* __restrict__ b2,
    unsigned short* __restrict__ C, int M, int N, int K, int dogelu)
{
  __shared__ unsigned short As[128*64];
  __shared__ unsigned short Bs[128*64];
  int gswz = blockIdx.x;
  int chunkg = gridDim.x >> 3;
  int bid = (gswz & 7)*chunkg + (gswz >> 3);
  int tid = threadIdx.x;
  int nT = N >> 7;
  int tm = bid / nT;
  int tn = bid - tm*nT;
  int which = (tn << 7) / 768;
  const float* bp = (which == 0) ? b0 : (which == 1) ? b1 : b2;
  bp -= which * 768;
  int wave = tid >> 6, lane = tid & 63;
  int wm = (wave >> 1) << 6;
  int wn = (wave & 1) << 6;
  int fr = lane & 15;
  int g  = lane >> 4;

  size_t aoff[4], woff[4];
  int ldsb[4];
#pragma unroll
  for (int s4 = 0; s4 < 4; s4++){
    int ob = s4*4096 + tid*16;
    int r  = ob >> 7;
    int p  = (ob >> 4) & 7;
    int l  = p ^ (r & 7);
    aoff[s4] = ((size_t)(tm*128 + r)*K)*2 + l*16;
    woff[s4] = ((size_t)(tn*128 + r)*K)*2 + l*16;
    ldsb[s4] = s4*4096 + wave*1024;
  }
  const char* Ab = (const char*)A;
  const char* Wb = (const char*)W;
  char* AsB = (char*)As;
  char* BsB = (char*)Bs;

  f32x4 acc[4][4];
#pragma unroll
  for (int m = 0; m < 4; m++)
#pragma unroll
    for (int n = 0; n < 4; n++) acc[m][n] = (f32x4){0.f,0.f,0.f,0.f};

  for (int k0 = 0; k0 < K; k0 += 64){
    size_t kb = (size_t)k0*2;
#pragma unroll
    for (int s4 = 0; s4 < 4; s4++) gload16(Ab + aoff[s4] + kb, AsB + ldsb[s4]);
#pragma unroll
    for (int s4 = 0; s4 < 4; s4++) gload16(Wb + woff[s4] + kb, BsB + ldsb[s4]);
    __syncthreads();

    f16x8 af[4], bf[4];
#pragma unroll
    for (int m = 0; m < 4; m++){
      int row = wm + m*16 + fr;
      af[m] = __builtin_bit_cast(f16x8, *(const us8*)(AsB + row*128 + ((g ^ (row & 7))*16)));
    }
#pragma unroll
    for (int n = 0; n < 4; n++){
      int row = wn + n*16 + fr;
      bf[n] = __builtin_bit_cast(f16x8, *(const us8*)(BsB + row*128 + ((g ^ (row & 7))*16)));
    }
#pragma unroll
    for (int m = 0; m < 4; m++)
#pragma unroll
      for (int n = 0; n < 4; n++)
        acc[m][n] = __builtin_amdgcn_mfma_f32_16x16x32_f16(af[m], bf[n], acc[m][n], 0, 0, 0);

#pragma unroll
    for (int m = 0; m < 4; m++){
      int row = wm + m*16 + fr;
      af[m] = __builtin_bit_cast(f16x8, *(const us8*)(AsB + row*128 + (((g+4) ^ (row & 7))*16)));
    }
#pragma unroll
    for (int n = 0; n < 4; n++){
      int row = wn + n*16 + fr;
      bf[n] = __builtin_bit_cast(f16x8, *(const us8*)(BsB + row*128 + (((g+4) ^ (row & 7))*16)));
    }
#pragma unroll
    for (int m = 0; m < 4; m++)
#pragma unroll
      for (int n = 0; n < 4; n++)
        acc[m][n] = __builtin_amdgcn_mfma_f32_16x16x32_f16(af[m], bf[n], acc[m][n], 0, 0, 0);
    __syncthreads();
  }

#pragma unroll
  for (int n = 0; n < 4; n++){
    int col = tn*128 + wn + n*16 + fr;
    float bv = bp[col];
#pragma unroll
    for (int m = 0; m < 4; m++){
      int row = tm*128 + wm + m*16 + g*4;
#pragma unroll
      for (int q = 0; q < 4; q++){
        float v = acc[m][n][q] + bv;
        if (dogelu) v = 0.5f*v*(1.0f + erff(v*0.70710678118654752f));
        C[(size_t)(row + q)*N + col] = f2h(v);
      }
    }
  }
}

// ---------------- prep: u_c[b,h,j] = sum_d v*Wf_c ; negv[b,j] ----------------
__global__ __launch_bounds__(256) void prep_kernel(
    const unsigned short* __restrict__ qkv, const float* __restrict__ mask,
    const float* __restrict__ Wf1, const float* __restrict__ Wf2, const float* __restrict__ Wf3,
    float* __restrict__ uarr,   // [B*NH][3][N]
    float* __restrict__ negv)   // [B][N]
{
  int bh = blockIdx.x;
  int h = bh & 31, b = bh >> 5;
  int j = threadIdx.x;
  const unsigned short* vr = qkv + (size_t)(b*N_ + j)*QKVN + 1536 + h*D_;
  us8 v0 = *(const us8*)(vr);
  us8 v1 = *(const us8*)(vr + 8);
  us8 v2 = *(const us8*)(vr + 16);
  const float* w1 = Wf1 + h*D_;
  const float* w2 = Wf2 + h*D_;
  const float* w3 = Wf3 + h*D_;
  float u0 = 0.f, u1 = 0.f, u2 = 0.f;
#pragma unroll
  for (int e = 0; e < 8; e++){
    float va = h2f(v0[e]), vb2 = h2f(v1[e]), vc = h2f(v2[e]);
    u0 += va*w1[e] + vb2*w1[8+e] + vc*w1[16+e];
    u1 += va*w2[e] + vb2*w2[8+e] + vc*w2[16+e];
    u2 += va*w3[e] + vb2*w3[8+e] + vc*w3[16+e];
  }
  float* ub = uarr + (size_t)bh*3*N_;
  ub[j] = u0; ub[N_ + j] = u1; ub[2*N_ + j] = u2;
  if (h == 0) negv[b*N_ + j] = (1.0f - mask[b*N_ + j]) * -100000.0f;
}

// ---------------- attention + fused epilogue ----------------
// grid: B*NH*8 = 8192 (XCD swizzle: 4 consecutive b per XCD -> dpH L2-resident).
// block: 256 thr = 4 waves; one (b,h), 32 q-rows. wave: rg=w>>1 (16 rows), ch=w&1 (128 cols).
// bias+neg folded into MFMA C-in (x sqrt(24)); dp read as fp16 planes dpH[b][c][i][j].
#define SCALE 0.20412414523193154f   // 24^-0.5
#define INVSCALE 4.898979485566356f  // sqrt(24)
__global__ __launch_bounds__(256, 2) void attn_kernel(
    const unsigned short* __restrict__ qkv,
    const float* __restrict__ bias,
    const float* __restrict__ uarr, const float* __restrict__ negv,
    const unsigned short* __restrict__ dpH,
    float* __restrict__ fpart)
{
  int gswz = blockIdx.x;
  int lin = (gswz & 7)*1024 + (gswz >> 3);   // 8192 = 8*1024
  int qb4 = lin & 7;
  int bh = lin >> 3;
  int h = bh & 31, b = bh >> 5;
  int i0 = qb4*32;
  int t = threadIdx.x;

  __shared__ us8 Kp[256][5];      // 20 KB
  __shared__ us8 Qp[32][5];       // 2.5 KB
  __shared__ float u0s[256], u1s[256], u2s[256];
  __shared__ float negs[256];
  __shared__ float redm[2][16][2];
  __shared__ float4 redv[2][16][2];

  {
    us8 z = {0,0,0,0,0,0,0,0};
    const unsigned short* kr = qkv + (size_t)(b*N_ + t)*QKVN + 768 + h*D_;
    Kp[t][0] = *(const us8*)(kr);
    Kp[t][1] = *(const us8*)(kr + 8);
    Kp[t][2] = *(const us8*)(kr + 16);
    Kp[t][3] = z;
    const float* ub = uarr + (size_t)bh*3*N_;
    u0s[t] = ub[t]; u1s[t] = ub[N_ + t]; u2s[t] = ub[2*N_ + t];
    negs[t] = negv[b*N_ + t];
    if (t < 128){
      int iq = t >> 2, part = t & 3;
      const unsigned short* qr = qkv + (size_t)(b*N_ + i0 + iq)*QKVN + h*D_;
      Qp[iq][part] = (part < 3) ? *(const us8*)(qr + part*8) : z;
    }
  }

  int wave = t >> 6, lane = t & 63;
  int rg = wave >> 1, ch = wave & 1;
  int fr = lane & 15, g = lane >> 4;
  int il = rg*16 + fr;            // local row 0..31
  int ig = i0 + il;               // global row

  // bias prefetch (in flight across staging barrier)
  const float4* bias4 = (const float4*)(bias + ((size_t)bh*N_ + ig)*N_ + ch*128);
  float4 bvv[8];
#pragma unroll
  for (int jt = 0; jt < 8; jt++) bvv[jt] = bias4[jt*4 + g];

  __syncthreads();

  // scores: raw = q.k + (bias+neg)*sqrt(24); true score = raw * SCALE
  f16x8 qf = __builtin_bit_cast(f16x8, Qp[il][g]);
  f32x4 s[8];
#pragma unroll
  for (int jt = 0; jt < 8; jt++){
    int jb = ch*128 + jt*16 + g*4;
    float4 nv = *(const float4*)&negs[jb];
    f32x4 cin;
    cin[0] = (bvv[jt].x + nv.x)*INVSCALE;
    cin[1] = (bvv[jt].y + nv.y)*INVSCALE;
    cin[2] = (bvv[jt].z + nv.z)*INVSCALE;
    cin[3] = (bvv[jt].w + nv.w)*INVSCALE;
    f16x8 kf = __builtin_bit_cast(f16x8, Kp[ch*128 + jt*16 + fr][g]);
    s[jt] = __builtin_amdgcn_mfma_f32_16x16x32_f16(kf, qf, cin, 0, 0, 0);
  }

  // own-half row max
  float m = -3.0e38f;
#pragma unroll
  for (int jt = 0; jt < 8; jt++)
    m = fmaxf(m, fmaxf(fmaxf(s[jt][0], s[jt][1]), fmaxf(s[jt][2], s[jt][3])));
  m = fmaxf(m, __shfl_xor(m, 16));
  m = fmaxf(m, __shfl_xor(m, 32));
  if (lane < 16) redm[rg][fr][ch] = m;

  // issue ALL dp loads (fp16 planes); latency hides under the max barrier
  const unsigned short* dpb0 = dpH + ((size_t)(b*3)*N_ + ig)*N_ + ch*128;
  us4v dpre[8][3];
#pragma unroll
  for (int jt = 0; jt < 8; jt++){
    int off = jt*16 + g*4;
    dpre[jt][0] = *(const us4v*)(dpb0 + off);
    dpre[jt][1] = *(const us4v*)(dpb0 + (size_t)N_*N_ + off);
    dpre[jt][2] = *(const us4v*)(dpb0 + 2*(size_t)N_*N_ + off);
  }
  __syncthreads();
  m = fmaxf(redm[rg][fr][0], redm[rg][fr][1]);   // full row max

  float sum = 0.f, a0 = 0.f, a1 = 0.f, a2 = 0.f;
#pragma unroll
  for (int jt = 0; jt < 8; jt++){
    int j0 = ch*128 + jt*16 + g*4;
    float p0 = __expf((s[jt][0] - m)*SCALE);
    float p1 = __expf((s[jt][1] - m)*SCALE);
    float p2 = __expf((s[jt][2] - m)*SCALE);
    float p3 = __expf((s[jt][3] - m)*SCALE);
    sum += p0 + p1 + p2 + p3;
    float4 u0v = *(const float4*)&u0s[j0];
    float4 u1v = *(const float4*)&u1s[j0];
    float4 u2v = *(const float4*)&u2s[j0];
    us4v d0 = dpre[jt][0], d1 = dpre[jt][1], d2 = dpre[jt][2];
    a0 += p0*u0v.x*h2f(d0[0]) + p1*u0v.y*h2f(d0[1]) + p2*u0v.z*h2f(d0[2]) + p3*u0v.w*h2f(d0[3]);
    a1 += p0*u1v.x*h2f(d1[0]) + p1*u1v.y*h2f(d1[1]) + p2*u1v.z*h2f(d1[2]) + p3*u1v.w*h2f(d1[3]);
    a2 += p0*u2v.x*h2f(d2[0]) + p1*u2v.y*h2f(d2[1]) + p2*u2v.z*h2f(d2[2]) + p3*u2v.w*h2f(d2[3]);
  }
  sum += __shfl_xor(sum, 16); sum += __shfl_xor(sum, 32);
  a0  += __shfl_xor(a0, 16);  a0  += __shfl_xor(a0, 32);
  a1  += __shfl_xor(a1, 16);  a1  += __shfl_xor(a1, 32);
  a2  += __shfl_xor(a2, 16);  a2  += __shfl_xor(a2, 32);
  if (lane < 16) redv[rg][fr][ch] = make_float4(sum, a0, a1, a2);
  __syncthreads();

  if (t < 32){
    float4 v0 = redv[t >> 4][t & 15][0];
    float4 v1 = redv[t >> 4][t & 15][1];
    float rs = 1.0f / (v0.x + v1.x);
    float* fp = fpart + ((size_t)bh*N_ + i0 + t)*3;
    fp[0] = (v0.y + v1.y)*rs;
    fp[1] = (v0.z + v1.z)*rs;
    fp[2] = (v0.w + v1.w)*rs;
  }
}

// ---------------- final cross-head reduction ----------------
__global__ __launch_bounds__(256) void final_kernel(const float* __restrict__ fpart,
    const float* __restrict__ bf1, const float* __restrict__ bf2, const float* __restrict__ bf3,
    float* __restrict__ out)
{
  int idx = blockIdx.x*256 + threadIdx.x;
  if (idx >= B_*N_*3) return;
  int c = idx % 3;
  int bi = idx / 3;
  int b = bi >> 8, ii = bi & 255;
  float sacc = (c == 0) ? bf1[0] : (c == 1) ? bf2[0] : bf3[0];
#pragma unroll 8
  for (int hh = 0; hh < NH_; hh++){
    sacc += fpart[(((size_t)(b*NH_ + hh))*N_ + ii)*3 + c];
  }
  out[idx] = sacc;
}

extern "C" void kernel_launch(void* const* d_in, const int* in_sizes, int n_in,
                              void* d_out, int out_size, void* d_ws, size_t ws_size,
                              hipStream_t stream)
{
  const float* X    = (const float*)d_in[0];
  const float* bias = (const float*)d_in[1];
  const float* dp   = (const float*)d_in[2];
  const float* mask = (const float*)d_in[3];
  const float* Wi   = (const float*)d_in[4];
  const float* bi   = (const float*)d_in[5];
  const float* Wq   = (const float*)d_in[6];
  const float* bq   = (const float*)d_in[7];
  const float* Wk   = (const float*)d_in[8];
  const float* bk   = (const float*)d_in[9];
  const float* Wv   = (const float*)d_in[10];
  const float* bv   = (const float*)d_in[11];
  const float* Wf1  = (const float*)d_in[12];
  const float* bf1  = (const float*)d_in[13];
  const float* Wf2  = (const float*)d_in[14];
  const float* bf2  = (const float*)d_in[15];
  const float* Wf3  = (const float*)d_in[16];
  const float* bf3  = (const float*)d_in[17];
  float* out = (float*)d_out;

  unsigned short* xb   = (unsigned short*)d_ws;
  unsigned short* wib  = xb   + (size_t)M_*HS_;
  unsigned short* wqb  = wib  + (size_t)HS_*HS_;
  unsigned short* wkb  = wqb  + (size_t)HS_*HS_;
  unsigned short* wvb  = wkb  + (size_t)HS_*HS_;
  unsigned short* hb   = wvb  + (size_t)HS_*HS_;
  unsigned short* qkvb = hb   + (size_t)M_*HS_;
  float* fpart = (float*)(qkvb + (size_t)M_*QKVN);
  float* uarr  = fpart + (size_t)B_*NH_*N_*3;
  float* negv  = uarr + (size_t)B_*NH_*3*N_;
  unsigned short* dpH = (unsigned short*)(negv + (size_t)B_*N_);

  {
    int n4 = M_*HS_/4;
    cvt_kernel<<<n4/256, 256, 0, stream>>>(X, xb, n4);
    int w4 = HS_*HS_/4;
    cvt_kernel<<<w4/256, 256, 0, stream>>>(Wi, wib, w4);
    cvt_kernel<<<w4/256, 256, 0, stream>>>(Wq, wqb, w4);
    cvt_kernel<<<w4/256, 256, 0, stream>>>(Wk, wkb, w4);
    cvt_kernel<<<w4/256, 256, 0, stream>>>(Wv, wvb, w4);
    cvt_dp_kernel<<<(B_*N_*64)/256, 256, 0, stream>>>(dp, dpH);
  }

  // h = gelu(X Wi^T + bi):  grid 64*6 = 384 (%8==0)
  gemm128_kernel<<<(M_/128)*(HS_/128), 256, 0, stream>>>(xb, wib, bi, bi, bi, hb, M_, HS_, HS_, 1);
  // qkv = h [Wq;Wk;Wv]^T + bias:  grid 64*18 = 1152 (%8==0)
  gemm128_kernel<<<(M_/128)*(QKVN/128), 256, 0, stream>>>(hb, wqb, bq, bk, bv, qkvb, M_, QKVN, HS_, 0);

  prep_kernel<<<B_*NH_, 256, 0, stream>>>(qkvb, mask, Wf1, Wf2, Wf3, uarr, negv);

  attn_kernel<<<B_*NH_*8, 256, 0, stream>>>(qkvb, bias, uarr, negv, dpH, fpart);

  final_kernel<<<(B_*N_*3 + 255)/256, 256, 0, stream>>>(fpart, bf1, bf2, bf3, out);
}

// Round 8
// 235.555 us; speedup vs baseline: 2.3543x; 1.0311x over previous
//
#include <hip/hip_runtime.h>
#include <hip/hip_fp16.h>

#define B_  32
#define N_  256
#define HS_ 768
#define NH_ 32
#define D_  24
#define M_  (B_*N_)   // 8192
#define QKVN 2304

typedef unsigned short us8 __attribute__((ext_vector_type(8)));
typedef _Float16 f16x8 __attribute__((ext_vector_type(8)));
typedef float f32x4 __attribute__((ext_vector_type(4)));

__device__ __forceinline__ unsigned short f2h(float x){
  return __half_as_ushort(__float2half(x));
}
__device__ __forceinline__ float h2f(unsigned short u){
  return __half2float(__ushort_as_half(u));
}
__device__ __forceinline__ void gload16(const void* g, void* l){
  __builtin_amdgcn_global_load_lds(
      (const __attribute__((address_space(1))) void*)g,
      (__attribute__((address_space(3))) void*)l, 16, 0, 0);
}

// ---------------- fp32 -> fp16-bits conversion ----------------
__global__ __launch_bounds__(256) void cvt_kernel(const float* __restrict__ in,
                                                  unsigned short* __restrict__ out, int n4){
  int i = blockIdx.x*256 + threadIdx.x;
  if (i >= n4) return;
  float4 v = ((const float4*)in)[i];
  ushort4 o;
  o.x = f2h(v.x); o.y = f2h(v.y); o.z = f2h(v.z); o.w = f2h(v.w);
  ((ushort4*)out)[i] = o;
}

// ---------------- GEMM 128x128, BK=64, global_load_lds, XOR-swizzled LDS ----------------
__global__ __launch_bounds__(256) void gemm128_kernel(
    const unsigned short* __restrict__ A, const unsigned short* __restrict__ W,
    const float* __restrict__ b0, const float* __restrict__ b1, const float* __restrict__ b2,
    unsigned short* __restrict__ C, int M, int N, int K, int dogelu)
{
  __shared__ unsigned short As[128*64];
  __shared__ unsigned short Bs[128*64];
  int gswz = blockIdx.x;
  int chunkg = gridDim.x >> 3;
  int bid = (gswz & 7)*chunkg + (gswz >> 3);
  int tid = threadIdx.x;
  int nT = N >> 7;
  int tm = bid / nT;
  int tn = bid - tm*nT;
  int which = (tn << 7) / 768;
  const float* bp = (which == 0) ? b0 : (which == 1) ? b1 : b2;
  bp -= which * 768;
  int wave = tid >> 6, lane = tid & 63;
  int wm = (wave >> 1) << 6;
  int wn = (wave & 1) << 6;
  int fr = lane & 15;
  int g  = lane >> 4;

  size_t aoff[4], woff[4];
  int ldsb[4];
#pragma unroll
  for (int s4 = 0; s4 < 4; s4++){
    int ob = s4*4096 + tid*16;
    int r  = ob >> 7;
    int p  = (ob >> 4) & 7;
    int l  = p ^ (r & 7);
    aoff[s4] = ((size_t)(tm*128 + r)*K)*2 + l*16;
    woff[s4] = ((size_t)(tn*128 + r)*K)*2 + l*16;
    ldsb[s4] = s4*4096 + wave*1024;
  }
  const char* Ab = (const char*)A;
  const char* Wb = (const char*)W;
  char* AsB = (char*)As;
  char* BsB = (char*)Bs;

  f32x4 acc[4][4];
#pragma unroll
  for (int m = 0; m < 4; m++)
#pragma unroll
    for (int n = 0; n < 4; n++) acc[m][n] = (f32x4){0.f,0.f,0.f,0.f};

  for (int k0 = 0; k0 < K; k0 += 64){
    size_t kb = (size_t)k0*2;
#pragma unroll
    for (int s4 = 0; s4 < 4; s4++) gload16(Ab + aoff[s4] + kb, AsB + ldsb[s4]);
#pragma unroll
    for (int s4 = 0; s4 < 4; s4++) gload16(Wb + woff[s4] + kb, BsB + ldsb[s4]);
    __syncthreads();

    f16x8 af[4], bf[4];
#pragma unroll
    for (int m = 0; m < 4; m++){
      int row = wm + m*16 + fr;
      af[m] = __builtin_bit_cast(f16x8, *(const us8*)(AsB + row*128 + ((g ^ (row & 7))*16)));
    }
#pragma unroll
    for (int n = 0; n < 4; n++){
      int row = wn + n*16 + fr;
      bf[n] = __builtin_bit_cast(f16x8, *(const us8*)(BsB + row*128 + ((g ^ (row & 7))*16)));
    }
#pragma unroll
    for (int m = 0; m < 4; m++)
#pragma unroll
      for (int n = 0; n < 4; n++)
        acc[m][n] = __builtin_amdgcn_mfma_f32_16x16x32_f16(af[m], bf[n], acc[m][n], 0, 0, 0);

#pragma unroll
    for (int m = 0; m < 4; m++){
      int row = wm + m*16 + fr;
      af[m] = __builtin_bit_cast(f16x8, *(const us8*)(AsB + row*128 + (((g+4) ^ (row & 7))*16)));
    }
#pragma unroll
    for (int n = 0; n < 4; n++){
      int row = wn + n*16 + fr;
      bf[n] = __builtin_bit_cast(f16x8, *(const us8*)(BsB + row*128 + (((g+4) ^ (row & 7))*16)));
    }
#pragma unroll
    for (int m = 0; m < 4; m++)
#pragma unroll
      for (int n = 0; n < 4; n++)
        acc[m][n] = __builtin_amdgcn_mfma_f32_16x16x32_f16(af[m], bf[n], acc[m][n], 0, 0, 0);
    __syncthreads();
  }

#pragma unroll
  for (int n = 0; n < 4; n++){
    int col = tn*128 + wn + n*16 + fr;
    float bv = bp[col];
#pragma unroll
    for (int m = 0; m < 4; m++){
      int row = tm*128 + wm + m*16 + g*4;
#pragma unroll
      for (int q = 0; q < 4; q++){
        float v = acc[m][n][q] + bv;
        if (dogelu) v = 0.5f*v*(1.0f + erff(v*0.70710678118654752f));
        C[(size_t)(row + q)*N + col] = f2h(v);
      }
    }
  }
}

// ---------------- prep: u_c[b,h,j] = sum_d v*Wf_c ; negv[b,j] ----------------
__global__ __launch_bounds__(256) void prep_kernel(
    const unsigned short* __restrict__ qkv, const float* __restrict__ mask,
    const float* __restrict__ Wf1, const float* __restrict__ Wf2, const float* __restrict__ Wf3,
    float* __restrict__ uarr,   // [B*NH][3][N]
    float* __restrict__ negv)   // [B][N]
{
  int bh = blockIdx.x;
  int h = bh & 31, b = bh >> 5;
  int j = threadIdx.x;
  const unsigned short* vr = qkv + (size_t)(b*N_ + j)*QKVN + 1536 + h*D_;
  us8 v0 = *(const us8*)(vr);
  us8 v1 = *(const us8*)(vr + 8);
  us8 v2 = *(const us8*)(vr + 16);
  const float* w1 = Wf1 + h*D_;
  const float* w2 = Wf2 + h*D_;
  const float* w3 = Wf3 + h*D_;
  float u0 = 0.f, u1 = 0.f, u2 = 0.f;
#pragma unroll
  for (int e = 0; e < 8; e++){
    float va = h2f(v0[e]), vb2 = h2f(v1[e]), vc = h2f(v2[e]);
    u0 += va*w1[e] + vb2*w1[8+e] + vc*w1[16+e];
    u1 += va*w2[e] + vb2*w2[8+e] + vc*w2[16+e];
    u2 += va*w3[e] + vb2*w3[8+e] + vc*w3[16+e];
  }
  float* ub = uarr + (size_t)bh*3*N_;
  ub[j] = u0; ub[N_ + j] = u1; ub[2*N_ + j] = u2;
  if (h == 0) negv[b*N_ + j] = (1.0f - mask[b*N_ + j]) * -100000.0f;
}

// ---------------- attention + fused epilogue ----------------
// grid: B*NH = 1024 (XCD swizzle groups same-b blocks -> dp/qkv L2-resident).
// block: 256 thr = 4 waves; one (b,h); 16 chunks of 16 q-rows.
// wave = 16 rows x 64 cols (ch = wave). Fixed softmax max M0=16 (scores <= ~7):
// p = exp(s - 16); row-normalization by sum makes this exact. No max reduce needed.
// bias: streamed fp32 via global_load_lds, double-buffered, XOR-pre-swizzled source.
// dp: fp32 direct, depth-1 register prefetch with static A/B buffers.
#define SCALE 0.20412414523193154f   // 24^-0.5
#define INVSCALE 4.898979485566356f  // sqrt(24)
#define M0 16.0f
__global__ __launch_bounds__(256) void attn_kernel(
    const unsigned short* __restrict__ qkv,
    const float* __restrict__ bias,
    const float* __restrict__ uarr, const float* __restrict__ negv,
    const float* __restrict__ dp,
    float* __restrict__ fpart)
{
  int gswz = blockIdx.x;
  int lin = (gswz & 7)*128 + (gswz >> 3);   // 1024 = 8*128; 4 b's per XCD
  int h = lin & 31, b = lin >> 5;
  int t = threadIdx.x;

  __shared__ float biasS[2][4096];   // 2 x 16KB: 16 rows x 1KB, phys chunk-swizzled
  __shared__ us8 Kp[256][5];         // 20 KB (chunk3 = zeros, chunk4 pad)
  __shared__ us8 Qp[256][5];         // 20 KB
  __shared__ float u0s[256], u1s[256], u2s[256];
  __shared__ float negs[256];
  __shared__ float4 redv[2][4][16];

  int wave = t >> 6, lane = t & 63;
  int ch = wave, fr = lane & 15, g = lane >> 4;

  // bias gload offsets (4 rounds x 16B/thread = 16KB); source pre-swizzled so
  // phys chunk pc at (row, pc) holds logical chunk pc^(row&7)  [both-sides rule]
  int srcoff[4], ldsoff[4];
#pragma unroll
  for (int r = 0; r < 4; r++){
    int a   = r*4096 + t*16;          // linear LDS byte offset
    int row = a >> 10;                // 0..15
    int pc  = (a >> 4) & 63;
    int lc  = pc ^ (row & 7);
    srcoff[r] = row*1024 + lc*16;
    ldsoff[r] = r*4096 + wave*1024;   // wave-uniform; HW adds lane*16
  }
  const char* biasC = (const char*)(bias + (size_t)lin*N_*N_);

  #define ISSUE_BIAS(c1)  do { \
    const char* _s = biasC + (c1)*16384; \
    char* _d = (char*)biasS[(c1) & 1]; \
    _Pragma("unroll") \
    for (int _r = 0; _r < 4; _r++) gload16(_s + srcoff[_r], _d + ldsoff[_r]); \
  } while(0)

  const float* dpbase = dp + (size_t)b*N_*768 + (ch*64 + g*4)*3;
  #define ISSUE_DP(c1, buf)  do { \
    const float* _p = dpbase + (size_t)((c1)*16 + fr)*768; \
    _Pragma("unroll") \
    for (int _jt = 0; _jt < 4; _jt++){ \
      const float4* _q = (const float4*)(_p + _jt*48); \
      buf[_jt*3+0] = _q[0]; buf[_jt*3+1] = _q[1]; buf[_jt*3+2] = _q[2]; \
    } \
  } while(0)

  // ---- prologue: start bias[0] + dp[0], stage K/Q/u/neg ----
  ISSUE_BIAS(0);
  float4 dpA[12], dpB[12];
  ISSUE_DP(0, dpA);
  {
    us8 z = {0,0,0,0,0,0,0,0};
    const unsigned short* kr = qkv + (size_t)(b*N_ + t)*QKVN + 768 + h*D_;
    Kp[t][0] = *(const us8*)(kr);
    Kp[t][1] = *(const us8*)(kr + 8);
    Kp[t][2] = *(const us8*)(kr + 16);
    Kp[t][3] = z;
    const unsigned short* qr = kr - 768;
    Qp[t][0] = *(const us8*)(qr);
    Qp[t][1] = *(const us8*)(qr + 8);
    Qp[t][2] = *(const us8*)(qr + 16);
    Qp[t][3] = z;
    const float* ub = uarr + (size_t)lin*3*N_;
    u0s[t] = ub[t]; u1s[t] = ub[N_ + t]; u2s[t] = ub[2*N_ + t];
    negs[t] = negv[b*N_ + t];
  }
  __syncthreads();

  // ---- chunk body (par is a literal at each call site) ----
  auto do_chunk = [&](int c, int par, float4 (&dcur)[12], float4 (&dnxt)[12])
      __attribute__((always_inline)) {
    if (c < 15){
      ISSUE_BIAS(c+1);
      ISSUE_DP(c+1, dnxt);
    }
    f16x8 qf = __builtin_bit_cast(f16x8, Qp[c*16 + fr][g]);
    const char* bbuf = (const char*)biasS[par];
    int swz = (fr & 7) << 4;
    float sum = 0.f, a0 = 0.f, a1 = 0.f, a2 = 0.f;
#pragma unroll
    for (int jt = 0; jt < 4; jt++){
      int j0 = ch*64 + jt*16 + g*4;
      float4 bv = *(const float4*)(bbuf + fr*1024 + ((j0 << 2) ^ swz));
      float4 nv = *(const float4*)&negs[j0];
      f32x4 cin;
      cin[0] = (bv.x + nv.x)*INVSCALE;
      cin[1] = (bv.y + nv.y)*INVSCALE;
      cin[2] = (bv.z + nv.z)*INVSCALE;
      cin[3] = (bv.w + nv.w)*INVSCALE;
      f16x8 kf = __builtin_bit_cast(f16x8, Kp[ch*64 + jt*16 + fr][g]);
      f32x4 sv = __builtin_amdgcn_mfma_f32_16x16x32_f16(kf, qf, cin, 0, 0, 0);
      float p0 = __expf(fmaf(sv[0], SCALE, -M0));
      float p1 = __expf(fmaf(sv[1], SCALE, -M0));
      float p2 = __expf(fmaf(sv[2], SCALE, -M0));
      float p3 = __expf(fmaf(sv[3], SCALE, -M0));
      sum += p0 + p1 + p2 + p3;
      float4 u0v = *(const float4*)&u0s[j0];
      float4 u1v = *(const float4*)&u1s[j0];
      float4 u2v = *(const float4*)&u2s[j0];
      float4 d0 = dcur[jt*3], d1 = dcur[jt*3+1], d2 = dcur[jt*3+2];
      a0 += p0*u0v.x*d0.x + p1*u0v.y*d0.w + p2*u0v.z*d1.z + p3*u0v.w*d2.y;
      a1 += p0*u1v.x*d0.y + p1*u1v.y*d1.x + p2*u1v.z*d1.w + p3*u1v.w*d2.z;
      a2 += p0*u2v.x*d0.z + p1*u2v.y*d1.y + p2*u2v.z*d2.x + p3*u2v.w*d2.w;
    }
    sum += __shfl_xor(sum, 16); sum += __shfl_xor(sum, 32);
    a0  += __shfl_xor(a0, 16);  a0  += __shfl_xor(a0, 32);
    a1  += __shfl_xor(a1, 16);  a1  += __shfl_xor(a1, 32);
    a2  += __shfl_xor(a2, 16);  a2  += __shfl_xor(a2, 32);
    if (lane < 16) redv[par][ch][fr] = make_float4(sum, a0, a1, a2);
    __syncthreads();
    if (t < 16){
      float4 v0 = redv[par][0][t];
      float4 v1 = redv[par][1][t];
      float4 v2 = redv[par][2][t];
      float4 v3 = redv[par][3][t];
      float rs = 1.0f / (v0.x + v1.x + v2.x + v3.x);
      float* fp = fpart + ((size_t)lin*N_ + c*16 + t)*3;
      fp[0] = (v0.y + v1.y + v2.y + v3.y)*rs;
      fp[1] = (v0.z + v1.z + v2.z + v3.z)*rs;
      fp[2] = (v0.w + v1.w + v2.w + v3.w)*rs;
    }
  };

#pragma unroll 1
  for (int cc = 0; cc < 8; cc++){
    do_chunk(2*cc,     0, dpA, dpB);
    do_chunk(2*cc + 1, 1, dpB, dpA);
  }
  #undef ISSUE_BIAS
  #undef ISSUE_DP
}

// ---------------- final cross-head reduction ----------------
__global__ __launch_bounds__(256) void final_kernel(const float* __restrict__ fpart,
    const float* __restrict__ bf1, const float* __restrict__ bf2, const float* __restrict__ bf3,
    float* __restrict__ out)
{
  int idx = blockIdx.x*256 + threadIdx.x;
  if (idx >= B_*N_*3) return;
  int c = idx % 3;
  int bi = idx / 3;
  int b = bi >> 8, ii = bi & 255;
  float sacc = (c == 0) ? bf1[0] : (c == 1) ? bf2[0] : bf3[0];
#pragma unroll 8
  for (int hh = 0; hh < NH_; hh++){
    sacc += fpart[(((size_t)(b*NH_ + hh))*N_ + ii)*3 + c];
  }
  out[idx] = sacc;
}

extern "C" void kernel_launch(void* const* d_in, const int* in_sizes, int n_in,
                              void* d_out, int out_size, void* d_ws, size_t ws_size,
                              hipStream_t stream)
{
  const float* X    = (const float*)d_in[0];
  const float* bias = (const float*)d_in[1];
  const float* dp   = (const float*)d_in[2];
  const float* mask = (const float*)d_in[3];
  const float* Wi   = (const float*)d_in[4];
  const float* bi   = (const float*)d_in[5];
  const float* Wq   = (const float*)d_in[6];
  const float* bq   = (const float*)d_in[7];
  const float* Wk   = (const float*)d_in[8];
  const float* bk   = (const float*)d_in[9];
  const float* Wv   = (const float*)d_in[10];
  const float* bv   = (const float*)d_in[11];
  const float* Wf1  = (const float*)d_in[12];
  const float* bf1  = (const float*)d_in[13];
  const float* Wf2  = (const float*)d_in[14];
  const float* bf2  = (const float*)d_in[15];
  const float* Wf3  = (const float*)d_in[16];
  const float* bf3  = (const float*)d_in[17];
  float* out = (float*)d_out;

  unsigned short* xb   = (unsigned short*)d_ws;
  unsigned short* wib  = xb   + (size_t)M_*HS_;
  unsigned short* wqb  = wib  + (size_t)HS_*HS_;
  unsigned short* wkb  = wqb  + (size_t)HS_*HS_;
  unsigned short* wvb  = wkb  + (size_t)HS_*HS_;
  unsigned short* hb   = wvb  + (size_t)HS_*HS_;
  unsigned short* qkvb = hb   + (size_t)M_*HS_;
  float* fpart = (float*)(qkvb + (size_t)M_*QKVN);
  float* uarr  = fpart + (size_t)B_*NH_*N_*3;
  float* negv  = uarr + (size_t)B_*NH_*3*N_;

  {
    int n4 = M_*HS_/4;
    cvt_kernel<<<n4/256, 256, 0, stream>>>(X, xb, n4);
    int w4 = HS_*HS_/4;
    cvt_kernel<<<w4/256, 256, 0, stream>>>(Wi, wib, w4);
    cvt_kernel<<<w4/256, 256, 0, stream>>>(Wq, wqb, w4);
    cvt_kernel<<<w4/256, 256, 0, stream>>>(Wk, wkb, w4);
    cvt_kernel<<<w4/256, 256, 0, stream>>>(Wv, wvb, w4);
  }

  // h = gelu(X Wi^T + bi):  grid 64*6 = 384 (%8==0)
  gemm128_kernel<<<(M_/128)*(HS_/128), 256, 0, stream>>>(xb, wib, bi, bi, bi, hb, M_, HS_, HS_, 1);
  // qkv = h [Wq;Wk;Wv]^T + bias:  grid 64*18 = 1152 (%8==0)
  gemm128_kernel<<<(M_/128)*(QKVN/128), 256, 0, stream>>>(hb, wqb, bq, bk, bv, qkvb, M_, QKVN, HS_, 0);

  prep_kernel<<<B_*NH_, 256, 0, stream>>>(qkvb, mask, Wf1, Wf2, Wf3, uarr, negv);

  attn_kernel<<<B_*NH_, 256, 0, stream>>>(qkvb, bias, uarr, negv, dp, fpart);

  final_kernel<<<(B_*N_*3 + 255)/256, 256, 0, stream>>>(fpart, bf1, bf2, bf3, out);
}

// Round 9
// 181.399 us; speedup vs baseline: 3.0571x; 1.2985x over previous
//
#include <hip/hip_runtime.h>
#include <hip/hip_fp16.h>

#define B_  32
#define N_  256
#define HS_ 768
#define NH_ 32
#define D_  24
#define M_  (B_*N_)   // 8192
#define QKVN 2304

typedef unsigned short us8 __attribute__((ext_vector_type(8)));
typedef _Float16 f16x8 __attribute__((ext_vector_type(8)));
typedef float f32x4 __attribute__((ext_vector_type(4)));

__device__ __forceinline__ unsigned short f2h(float x){
  return __half_as_ushort(__float2half(x));
}
__device__ __forceinline__ float h2f(unsigned short u){
  return __half2float(__ushort_as_half(u));
}
__device__ __forceinline__ void gload16(const void* g, void* l){
  __builtin_amdgcn_global_load_lds(
      (const __attribute__((address_space(1))) void*)g,
      (__attribute__((address_space(3))) void*)l, 16, 0, 0);
}

// ---------------- fp32 -> fp16-bits conversion ----------------
__global__ __launch_bounds__(256) void cvt_kernel(const float* __restrict__ in,
                                                  unsigned short* __restrict__ out, int n4){
  int i = blockIdx.x*256 + threadIdx.x;
  if (i >= n4) return;
  float4 v = ((const float4*)in)[i];
  ushort4 o;
  o.x = f2h(v.x); o.y = f2h(v.y); o.z = f2h(v.z); o.w = f2h(v.w);
  ((ushort4*)out)[i] = o;
}

// ---------------- GEMM 128x128, BK=64, global_load_lds, XOR-swizzled LDS ----------------
__global__ __launch_bounds__(256) void gemm128_kernel(
    const unsigned short* __restrict__ A, const unsigned short* __restrict__ W,
    const float* __restrict__ b0, const float* __restrict__ b1, const float* __restrict__ b2,
    unsigned short* __restrict__ C, int M, int N, int K, int dogelu)
{
  __shared__ unsigned short As[128*64];
  __shared__ unsigned short Bs[128*64];
  int gswz = blockIdx.x;
  int chunkg = gridDim.x >> 3;
  int bid = (gswz & 7)*chunkg + (gswz >> 3);
  int tid = threadIdx.x;
  int nT = N >> 7;
  int tm = bid / nT;
  int tn = bid - tm*nT;
  int which = (tn << 7) / 768;
  const float* bp = (which == 0) ? b0 : (which == 1) ? b1 : b2;
  bp -= which * 768;
  int wave = tid >> 6, lane = tid & 63;
  int wm = (wave >> 1) << 6;
  int wn = (wave & 1) << 6;
  int fr = lane & 15;
  int g  = lane >> 4;

  size_t aoff[4], woff[4];
  int ldsb[4];
#pragma unroll
  for (int s4 = 0; s4 < 4; s4++){
    int ob = s4*4096 + tid*16;
    int r  = ob >> 7;
    int p  = (ob >> 4) & 7;
    int l  = p ^ (r & 7);
    aoff[s4] = ((size_t)(tm*128 + r)*K)*2 + l*16;
    woff[s4] = ((size_t)(tn*128 + r)*K)*2 + l*16;
    ldsb[s4] = s4*4096 + wave*1024;
  }
  const char* Ab = (const char*)A;
  const char* Wb = (const char*)W;
  char* AsB = (char*)As;
  char* BsB = (char*)Bs;

  f32x4 acc[4][4];
#pragma unroll
  for (int m = 0; m < 4; m++)
#pragma unroll
    for (int n = 0; n < 4; n++) acc[m][n] = (f32x4){0.f,0.f,0.f,0.f};

  for (int k0 = 0; k0 < K; k0 += 64){
    size_t kb = (size_t)k0*2;
#pragma unroll
    for (int s4 = 0; s4 < 4; s4++) gload16(Ab + aoff[s4] + kb, AsB + ldsb[s4]);
#pragma unroll
    for (int s4 = 0; s4 < 4; s4++) gload16(Wb + woff[s4] + kb, BsB + ldsb[s4]);
    __syncthreads();

    f16x8 af[4], bf[4];
#pragma unroll
    for (int m = 0; m < 4; m++){
      int row = wm + m*16 + fr;
      af[m] = __builtin_bit_cast(f16x8, *(const us8*)(AsB + row*128 + ((g ^ (row & 7))*16)));
    }
#pragma unroll
    for (int n = 0; n < 4; n++){
      int row = wn + n*16 + fr;
      bf[n] = __builtin_bit_cast(f16x8, *(const us8*)(BsB + row*128 + ((g ^ (row & 7))*16)));
    }
#pragma unroll
    for (int m = 0; m < 4; m++)
#pragma unroll
      for (int n = 0; n < 4; n++)
        acc[m][n] = __builtin_amdgcn_mfma_f32_16x16x32_f16(af[m], bf[n], acc[m][n], 0, 0, 0);

#pragma unroll
    for (int m = 0; m < 4; m++){
      int row = wm + m*16 + fr;
      af[m] = __builtin_bit_cast(f16x8, *(const us8*)(AsB + row*128 + (((g+4) ^ (row & 7))*16)));
    }
#pragma unroll
    for (int n = 0; n < 4; n++){
      int row = wn + n*16 + fr;
      bf[n] = __builtin_bit_cast(f16x8, *(const us8*)(BsB + row*128 + (((g+4) ^ (row & 7))*16)));
    }
#pragma unroll
    for (int m = 0; m < 4; m++)
#pragma unroll
      for (int n = 0; n < 4; n++)
        acc[m][n] = __builtin_amdgcn_mfma_f32_16x16x32_f16(af[m], bf[n], acc[m][n], 0, 0, 0);
    __syncthreads();
  }

#pragma unroll
  for (int n = 0; n < 4; n++){
    int col = tn*128 + wn + n*16 + fr;
    float bv = bp[col];
#pragma unroll
    for (int m = 0; m < 4; m++){
      int row = tm*128 + wm + m*16 + g*4;
#pragma unroll
      for (int q = 0; q < 4; q++){
        float v = acc[m][n][q] + bv;
        if (dogelu) v = 0.5f*v*(1.0f + erff(v*0.70710678118654752f));
        C[(size_t)(row + q)*N + col] = f2h(v);
      }
    }
  }
}

// ---------------- prep: u_c[b,h,j] = sum_d v*Wf_c ; negv[b,j] ----------------
__global__ __launch_bounds__(256) void prep_kernel(
    const unsigned short* __restrict__ qkv, const float* __restrict__ mask,
    const float* __restrict__ Wf1, const float* __restrict__ Wf2, const float* __restrict__ Wf3,
    float* __restrict__ uarr,   // [B*NH][3][N]
    float* __restrict__ negv)   // [B][N]
{
  int bh = blockIdx.x;
  int h = bh & 31, b = bh >> 5;
  int j = threadIdx.x;
  const unsigned short* vr = qkv + (size_t)(b*N_ + j)*QKVN + 1536 + h*D_;
  us8 v0 = *(const us8*)(vr);
  us8 v1 = *(const us8*)(vr + 8);
  us8 v2 = *(const us8*)(vr + 16);
  const float* w1 = Wf1 + h*D_;
  const float* w2 = Wf2 + h*D_;
  const float* w3 = Wf3 + h*D_;
  float u0 = 0.f, u1 = 0.f, u2 = 0.f;
#pragma unroll
  for (int e = 0; e < 8; e++){
    float va = h2f(v0[e]), vb2 = h2f(v1[e]), vc = h2f(v2[e]);
    u0 += va*w1[e] + vb2*w1[8+e] + vc*w1[16+e];
    u1 += va*w2[e] + vb2*w2[8+e] + vc*w2[16+e];
    u2 += va*w3[e] + vb2*w3[8+e] + vc*w3[16+e];
  }
  float* ub = uarr + (size_t)bh*3*N_;
  ub[j] = u0; ub[N_ + j] = u1; ub[2*N_ + j] = u2;
  if (h == 0) negv[b*N_ + j] = (1.0f - mask[b*N_ + j]) * -100000.0f;
}

// ---------------- attention, G-factorized, pipelined over heads ----------------
// grid: B*16chunks = 512 (2 blocks/CU exactly; XCD swizzle groups same-b).
// block: 256 thr = 4 waves; one (b, 16 q-rows). Loop h=0..31:
//   G_c[i,j] += (1/S_h)*exp(s_h)*u_c[h,j]   (G in 48 VGPR; j-split 64/wave)
// Epilogue: f_c[i] = sum_j G_c[i,j]*dp[i,j,c] + bf_c  (dp in 48 VGPR, loaded once)
// Per head: 8 global_load_lds (bias 16K | K 12K planes | u+q 4K) double-buffered,
// counted s_waitcnt vmcnt(8) + raw s_barrier (loads live across barriers).
#define SCALE 0.20412414523193154f   // 24^-0.5
#define INVSCALE 4.898979485566356f  // sqrt(24)
#define M0 16.0f
#define BUFSZ 32768
__global__ __launch_bounds__(256, 2) void attn_kernel(
    const unsigned short* __restrict__ qkv,
    const float* __restrict__ bias,
    const float* __restrict__ uarr, const float* __restrict__ negv,
    const float* __restrict__ dp,
    const float* __restrict__ bf1, const float* __restrict__ bf2, const float* __restrict__ bf3,
    float* __restrict__ out)
{
  int gswz = blockIdx.x;
  int lin = (gswz & 7)*64 + (gswz >> 3);   // 512 = 8*64
  int b = lin >> 4, chunk = lin & 15;
  int i0 = chunk*16;
  int t = threadIdx.x;
  int wave = t >> 6, lane = t & 63;
  int ch = wave, fr = lane & 15, g = lane >> 4;

  __shared__ __align__(16) char smem[72192];
  // buf0@0, buf1@32768: {bias 16K | K planes 12K @+16384 | u 3K + q 0.75K @+28672}
  char* zp     = smem + 65536;               // 4K zeros
  float* negsF = (float*)(smem + 69632);     // 1K
  float* redv  = (float*)(smem + 70656);     // [2][16][4] f32
  float4* redvE= (float4*)(smem + 71168);    // [16][4]

  // ---- per-thread staging constants ----
  int bsrc[4];
#pragma unroll
  for (int r = 0; r < 4; r++){
    int a = r*4096 + t*16;
    int row = a >> 10;
    int pc = (a >> 4) & 63;
    int lc = pc ^ (row & 7);
    bsrc[r] = row*1024 + lc*16;
  }
  const char* bb0 = (const char*)bias + (((size_t)(b*32)*256 + i0)*256)*4;  // +h*262144
  const char* kq0 = (const char*)(qkv + (size_t)(b*N_ + t)*QKVN + 768);     // +h*48 +c*16
  const char* ub0 = (const char*)(uarr + (size_t)(b*32)*768);               // +h*3072
  const char* uqsrc0;
  int uqstep;
  if (t < 192){ uqsrc0 = ub0 + t*16; uqstep = 3072; }
  else if (t < 240){
    int rr = (t-192)/3, cc = (t-192)%3;
    uqsrc0 = (const char*)(qkv + (size_t)(b*N_ + i0 + rr)*QKVN) + cc*16;    // +h*48
    uqstep = 48;
  } else { uqsrc0 = ub0; uqstep = 3072; }

  #define ISSUE(hh, nx) do { \
    const char* _bB = bb0 + (size_t)(hh)*262144; \
    _Pragma("unroll") \
    for (int _r = 0; _r < 4; _r++) gload16(_bB + bsrc[_r], (nx) + _r*4096 + wave*1024); \
    const char* _kB = kq0 + (hh)*48; \
    _Pragma("unroll") \
    for (int _c = 0; _c < 3; _c++) gload16(_kB + _c*16, (nx) + 16384 + _c*4096 + wave*1024); \
    gload16(uqsrc0 + (size_t)(hh)*uqstep, (nx) + 28672 + wave*1024); \
  } while(0)

  // ---- prologue ----
  ISSUE(0, smem);                       // head 0 -> buf0
  // dp loaded once: rows i0+fr, j = ch*64+jt*16+g*4 .. +3, packed [j][c]
  float4 dpre[12];
  {
    const float* dpb = dp + (size_t)(b*N_ + i0 + fr)*768;
#pragma unroll
    for (int jt = 0; jt < 4; jt++){
      const float4* q4 = (const float4*)(dpb + (ch*64 + jt*16 + g*4)*3);
      dpre[jt*3+0] = q4[0]; dpre[jt*3+1] = q4[1]; dpre[jt*3+2] = q4[2];
    }
  }
  *(us8*)(zp + t*16) = (us8){0,0,0,0,0,0,0,0};
  negsF[t] = negv[b*N_ + t];
  asm volatile("s_waitcnt lgkmcnt(0)" ::: "memory");

  f32x4 G[4][3];
#pragma unroll
  for (int jt = 0; jt < 4; jt++)
#pragma unroll
    for (int c = 0; c < 3; c++) G[jt][c] = (f32x4){0.f,0.f,0.f,0.f};

  int swz = (fr & 7) << 4;

#pragma unroll 1
  for (int h = 0; h < 32; h++){
    int par = h & 1;
    char* bufb = smem + par*BUFSZ;
    char* nxb  = smem + (par^1)*BUFSZ;
    if (h < 31){
      ISSUE(h+1, nxb);
      asm volatile("s_waitcnt vmcnt(8)" ::: "memory");
    } else {
      asm volatile("s_waitcnt vmcnt(0)" ::: "memory");
    }
    __builtin_amdgcn_s_barrier();      // buf[par] published

    // qf: Q row i0+fr, head h, chunk g (g==3 -> zeros)
    const char* qa = (g < 3) ? (bufb + 28672 + 3072 + fr*48 + g*16) : (zp + fr*16);
    f16x8 qf = __builtin_bit_cast(f16x8, *(const us8*)qa);

    float rowsum = 0.f;
    f32x4 tt[4][3];
#pragma unroll
    for (int jt = 0; jt < 4; jt++){
      int j0 = ch*64 + jt*16 + g*4;
      float4 bv = *(const float4*)(bufb + fr*1024 + ((j0*4) ^ swz));
      float4 nv = *(const float4*)&negsF[j0];
      f32x4 cin;
      cin[0] = (bv.x + nv.x)*INVSCALE;
      cin[1] = (bv.y + nv.y)*INVSCALE;
      cin[2] = (bv.z + nv.z)*INVSCALE;
      cin[3] = (bv.w + nv.w)*INVSCALE;
      int krow = ch*64 + jt*16 + fr;
      const char* ka = (g < 3) ? (bufb + 16384 + g*4096 + krow*16) : (zp + krow*16);
      f16x8 kf = __builtin_bit_cast(f16x8, *(const us8*)ka);
      f32x4 sv = __builtin_amdgcn_mfma_f32_16x16x32_f16(kf, qf, cin, 0, 0, 0);
      f32x4 p;
      p[0] = __expf(fmaf(sv[0], SCALE, -M0));
      p[1] = __expf(fmaf(sv[1], SCALE, -M0));
      p[2] = __expf(fmaf(sv[2], SCALE, -M0));
      p[3] = __expf(fmaf(sv[3], SCALE, -M0));
      rowsum += p[0] + p[1] + p[2] + p[3];
      const char* ub = bufb + 28672;
#pragma unroll
      for (int c = 0; c < 3; c++){
        f32x4 uv = __builtin_bit_cast(f32x4, *(const float4*)(ub + c*1024 + j0*4));
        tt[jt][c] = p * uv;
      }
    }
    rowsum += __shfl_xor(rowsum, 16);
    rowsum += __shfl_xor(rowsum, 32);
    if (lane < 16) redv[(par*16 + fr)*4 + ch] = rowsum;
    asm volatile("s_waitcnt lgkmcnt(0)" ::: "memory");
    __builtin_amdgcn_s_barrier();      // redv published; buf reads done
    float4 rv = *(const float4*)&redv[(par*16 + fr)*4];
    float rs = 1.0f / (rv.x + rv.y + rv.z + rv.w);
#pragma unroll
    for (int jt = 0; jt < 4; jt++)
#pragma unroll
      for (int c = 0; c < 3; c++){
        G[jt][c][0] = fmaf(rs, tt[jt][c][0], G[jt][c][0]);
        G[jt][c][1] = fmaf(rs, tt[jt][c][1], G[jt][c][1]);
        G[jt][c][2] = fmaf(rs, tt[jt][c][2], G[jt][c][2]);
        G[jt][c][3] = fmaf(rs, tt[jt][c][3], G[jt][c][3]);
      }
  }
  #undef ISSUE

  // ---- epilogue: contract G with dp ----
  float a0 = 0.f, a1 = 0.f, a2 = 0.f;
#pragma unroll
  for (int jt = 0; jt < 4; jt++){
    float4 d0 = dpre[jt*3], d1 = dpre[jt*3+1], d2 = dpre[jt*3+2];
    a0 += G[jt][0][0]*d0.x + G[jt][0][1]*d0.w + G[jt][0][2]*d1.z + G[jt][0][3]*d2.y;
    a1 += G[jt][1][0]*d0.y + G[jt][1][1]*d1.x + G[jt][1][2]*d1.w + G[jt][1][3]*d2.z;
    a2 += G[jt][2][0]*d0.z + G[jt][2][1]*d1.y + G[jt][2][2]*d2.x + G[jt][2][3]*d2.w;
  }
  a0 += __shfl_xor(a0, 16); a0 += __shfl_xor(a0, 32);
  a1 += __shfl_xor(a1, 16); a1 += __shfl_xor(a1, 32);
  a2 += __shfl_xor(a2, 16); a2 += __shfl_xor(a2, 32);
  if (lane < 16) redvE[fr*4 + ch] = make_float4(a0, a1, a2, 0.f);
  asm volatile("s_waitcnt lgkmcnt(0)" ::: "memory");
  __builtin_amdgcn_s_barrier();
  if (t < 16){
    float4 e0 = redvE[t*4+0], e1 = redvE[t*4+1], e2 = redvE[t*4+2], e3 = redvE[t*4+3];
    float* op = out + (size_t)(b*N_ + i0 + t)*3;
    op[0] = e0.x + e1.x + e2.x + e3.x + bf1[0];
    op[1] = e0.y + e1.y + e2.y + e3.y + bf2[0];
    op[2] = e0.z + e1.z + e2.z + e3.z + bf3[0];
  }
}

extern "C" void kernel_launch(void* const* d_in, const int* in_sizes, int n_in,
                              void* d_out, int out_size, void* d_ws, size_t ws_size,
                              hipStream_t stream)
{
  const float* X    = (const float*)d_in[0];
  const float* bias = (const float*)d_in[1];
  const float* dp   = (const float*)d_in[2];
  const float* mask = (const float*)d_in[3];
  const float* Wi   = (const float*)d_in[4];
  const float* bi   = (const float*)d_in[5];
  const float* Wq   = (const float*)d_in[6];
  const float* bq   = (const float*)d_in[7];
  const float* Wk   = (const float*)d_in[8];
  const float* bk   = (const float*)d_in[9];
  const float* Wv   = (const float*)d_in[10];
  const float* bv   = (const float*)d_in[11];
  const float* Wf1  = (const float*)d_in[12];
  const float* bf1  = (const float*)d_in[13];
  const float* Wf2  = (const float*)d_in[14];
  const float* bf2  = (const float*)d_in[15];
  const float* Wf3  = (const float*)d_in[16];
  const float* bf3  = (const float*)d_in[17];
  float* out = (float*)d_out;

  unsigned short* xb   = (unsigned short*)d_ws;
  unsigned short* wib  = xb   + (size_t)M_*HS_;
  unsigned short* wqb  = wib  + (size_t)HS_*HS_;
  unsigned short* wkb  = wqb  + (size_t)HS_*HS_;
  unsigned short* wvb  = wkb  + (size_t)HS_*HS_;
  unsigned short* hb   = wvb  + (size_t)HS_*HS_;
  unsigned short* qkvb = hb   + (size_t)M_*HS_;
  float* uarr  = (float*)(qkvb + (size_t)M_*QKVN);
  float* negv  = uarr + (size_t)B_*NH_*3*N_;

  {
    int n4 = M_*HS_/4;
    cvt_kernel<<<n4/256, 256, 0, stream>>>(X, xb, n4);
    int w4 = HS_*HS_/4;
    cvt_kernel<<<w4/256, 256, 0, stream>>>(Wi, wib, w4);
    cvt_kernel<<<w4/256, 256, 0, stream>>>(Wq, wqb, w4);
    cvt_kernel<<<w4/256, 256, 0, stream>>>(Wk, wkb, w4);
    cvt_kernel<<<w4/256, 256, 0, stream>>>(Wv, wvb, w4);
  }

  // h = gelu(X Wi^T + bi):  grid 64*6 = 384 (%8==0)
  gemm128_kernel<<<(M_/128)*(HS_/128), 256, 0, stream>>>(xb, wib, bi, bi, bi, hb, M_, HS_, HS_, 1);
  // qkv = h [Wq;Wk;Wv]^T + bias:  grid 64*18 = 1152 (%8==0)
  gemm128_kernel<<<(M_/128)*(QKVN/128), 256, 0, stream>>>(hb, wqb, bq, bk, bv, qkvb, M_, QKVN, HS_, 0);

  prep_kernel<<<B_*NH_, 256, 0, stream>>>(qkvb, mask, Wf1, Wf2, Wf3, uarr, negv);

  attn_kernel<<<B_*16, 256, 0, stream>>>(qkvb, bias, uarr, negv, dp,
                                         bf1, bf2, bf3, out);
}